// Round 1
// baseline (309.222 us; speedup 1.0000x reference)
//
#include <hip/hip_runtime.h>
#include <math.h>

// DSSIM (mean), B=32 C=3 H=W=512 fp32, separable 11x11 Gaussian.
// R5 = R4 (packed-FP32 sliding ring) + occupancy fix:
//  - RB 64 -> 32: RING 74 -> 42 rows, LDS 52 KB -> 29.6 KB => 5 blocks/CU
//    (20 waves/CU vs 12). Ring carries across chunks so h-phase total work
//    is unchanged; only barrier count doubles.
//  - h-phase re-tasked as 8 column-subtasks x 32 rows = 256 tasks/chunk so
//    all 256 threads stay busy (4-col subtask, 20-float window, 5x float4).
//    Weight index m = i - 3 - 2jp' is sub-independent (sub cancels).
//  - strip split into 4 row-segments of 128 rows: grid 1536 -> 6144 blocks,
//    kills the 6-blocks/CU-vs-capacity-5 dispatch tail. +10 halo rows per
//    segment (~+6% fetch, ~+8% h-rows).
//  - one atomicAdd per BLOCK (LDS reduce) keeps total atomics at 6144.
//  - NO lambdas/helpers (R3: un-inlined lambdas demote arrays to scratch).

namespace {
constexpr int IMG = 512;
constexpr int TW = 32;                 // strip width
constexpr int RB = 32;                 // output rows per chunk
constexpr int RING = RB + 10;          // 42 ring rows
constexpr int SLOT = 44;               // floats per (xg, ringrow) slot
constexpr int XGN = TW / 8;            // 4 col-groups
constexpr int SEGR = 128;              // rows per block segment
constexpr int NCHUNK = SEGR / RB;      // 4 chunks per segment
constexpr int SEGN = IMG / SEGR;       // 4 segments per strip
constexpr int CTILES = IMG / TW;       // 16 strips per image
constexpr int NIMG = 96;               // 32*3
constexpr float C1c = 1e-4f;
constexpr float C2c = 9e-4f;
constexpr float INV_N = 1.0f / 25165824.0f;  // 1/(96*512*512)
}

typedef float v2f __attribute__((ext_vector_type(2)));

__global__ void dssim_zero(float* ws) { ws[0] = 0.0f; }

__global__ void dssim_final(const float* __restrict__ ws, float* __restrict__ out) {
  out[0] = ws[0] * INV_N;
}

__global__ __launch_bounds__(256, 5) void dssim_main(
    const float* __restrict__ im1, const float* __restrict__ im2,
    const float* __restrict__ gk, float* __restrict__ ws)
{
  __shared__ float sR[XGN * RING * SLOT];   // 29,568 B -> 5 blocks/CU

  const int tid = threadIdx.x;
  const int bid = blockIdx.x;
  const int img = bid >> 6;          // 64 blocks per image (16 strips x 4 segs)
  const int rem = bid & 63;
  const int tsx = rem & 15;
  const int seg = rem >> 4;
  const int X0s = tsx * TW;
  const int Y0  = seg * SEGR;

  const float* __restrict__ p1 = im1 + (size_t)img * (IMG * IMG);
  const float* __restrict__ p2 = im2 + (size_t)img * (IMG * IMG);

  // k1[i] = k2d[i][5] / sqrt(k2d[5][5])  (separable, sum(k1)=1)
  float wt[11];
  {
    float ic = 1.0f / sqrtf(gk[5 * 11 + 5]);
    #pragma unroll
    for (int i = 0; i < 11; ++i) wt[i] = gk[i * 11 + 5] * ic;
  }
  // packed weight pairs: wp[m] = {wte(m), wte(m-1)}, wte zero-padded
  v2f wp[12];
  #pragma unroll
  for (int m = 0; m < 12; ++m) {
    float lo = (m <= 10) ? wt[m] : 0.f;
    float hi = (m >= 1) ? wt[m - 1] : 0.f;
    wp[m].x = lo; wp[m].y = hi;
  }

  // v-phase mapping: one column per thread, 4 rows (2 packed pairs)
  const int c   = tid & 31;
  const int yg  = tid >> 5;          // 0..7
  const int xg3 = c >> 3;
  const int cl  = c & 7;

  float lsum = 0.f;

  for (int kc = 0; kc < NCHUNK; ++kc) {
    // ---- h-phase: produce new h-rows into the ring ----
    // 8 column-subtasks per row (4 output cols each), all 256 threads busy.
    const int r0    = (kc == 0) ? -5 : RB * kc + 5;        // local row
    const int ntask = (kc == 0) ? 8 * RING : 8 * RB;       // 336 / 256
    for (int t = tid; t < ntask; t += 256) {
      const int colsub = t & 7;
      const int dr  = t >> 3;
      const int rl  = r0 + dr;                 // local row in [-5, SEGR+4]
      const int ry  = Y0 + rl;                 // global row
      const int rr  = (rl + 5) % RING;         // ring slot row
      const int xg  = colsub >> 1;
      const int sub = colsub & 1;
      const int cbs = X0s + xg * 8 + sub * 4 - 8;  // window col of w20[0], 4-aligned

      float a20[20], b20[20];
      if ((unsigned)ry < (unsigned)IMG) {
        const float* row1 = p1 + (size_t)ry * IMG;
        const float* row2 = p2 + (size_t)ry * IMG;
        if (cbs >= 0 && cbs + 20 <= IMG) {
          #pragma unroll
          for (int i = 0; i < 5; ++i) {
            float4 v1 = *(const float4*)(row1 + cbs + 4 * i);
            float4 v2 = *(const float4*)(row2 + cbs + 4 * i);
            a20[4*i+0] = v1.x; a20[4*i+1] = v1.y; a20[4*i+2] = v1.z; a20[4*i+3] = v1.w;
            b20[4*i+0] = v2.x; b20[4*i+1] = v2.y; b20[4*i+2] = v2.z; b20[4*i+3] = v2.w;
          }
        } else {
          #pragma unroll
          for (int e = 0; e < 20; ++e) {
            int cc = cbs + e;
            bool ok = (unsigned)cc < (unsigned)IMG;
            a20[e] = ok ? row1[cc] : 0.f;
            b20[e] = ok ? row2[cc] : 0.f;
          }
        }
      } else {
        #pragma unroll
        for (int e = 0; e < 20; ++e) { a20[e] = 0.f; b20[e] = 0.f; }
      }

      // two packed output pairs (4 cols) for this subtask
      v2f o0[2], o1[2], o2[2], o3[2], o4[2];
      #pragma unroll
      for (int jp = 0; jp < 2; ++jp) {
        o0[jp] = 0.f; o1[jp] = 0.f; o2[jp] = 0.f; o3[jp] = 0.f; o4[jp] = 0.f;
      }
      // window index i=3..16; m = i - 3 - 2*jp' (independent of sub)
      #pragma unroll
      for (int i = 3; i <= 16; ++i) {
        float va = a20[i], vb = b20[i];
        float pa = va * va, pb = vb * vb, pab = va * vb;
        v2f va2; va2.x = va; va2.y = va;
        v2f vb2; vb2.x = vb; vb2.y = vb;
        v2f pa2; pa2.x = pa; pa2.y = pa;
        v2f pb2; pb2.x = pb; pb2.y = pb;
        v2f pc2; pc2.x = pab; pc2.y = pab;
        if (i - 3 < 12) {                      // jp'=0, m = i-3
          v2f w = wp[i - 3];
          o0[0] = __builtin_elementwise_fma(w, va2, o0[0]);
          o1[0] = __builtin_elementwise_fma(w, vb2, o1[0]);
          o2[0] = __builtin_elementwise_fma(w, pa2, o2[0]);
          o3[0] = __builtin_elementwise_fma(w, pb2, o3[0]);
          o4[0] = __builtin_elementwise_fma(w, pc2, o4[0]);
        }
        if (i - 5 >= 0) {                      // jp'=1, m = i-5 (<=11 always)
          v2f w = wp[i - 5];
          o0[1] = __builtin_elementwise_fma(w, va2, o0[1]);
          o1[1] = __builtin_elementwise_fma(w, vb2, o1[1]);
          o2[1] = __builtin_elementwise_fma(w, pa2, o2[1]);
          o3[1] = __builtin_elementwise_fma(w, pb2, o3[1]);
          o4[1] = __builtin_elementwise_fma(w, pc2, o4[1]);
        }
      }

      const int base  = (xg * RING + rr) * SLOT;
      const int jbase = base + 16 * sub;       // global jpg = 2*sub + jp'
      *(float4*)&sR[jbase]      = make_float4(o0[0].x, o1[0].x, o2[0].x, o3[0].x);
      *(float4*)&sR[jbase + 4]  = make_float4(o0[0].y, o1[0].y, o2[0].y, o3[0].y);
      *(float4*)&sR[jbase + 8]  = make_float4(o0[1].x, o1[1].x, o2[1].x, o3[1].x);
      *(float4*)&sR[jbase + 12] = make_float4(o0[1].y, o1[1].y, o2[1].y, o3[1].y);
      *(float4*)&sR[base + 32 + 4 * sub] =
          make_float4(o4[0].x, o4[0].y, o4[1].x, o4[1].y);
    }
    __syncthreads();

    // ---- v-phase: 4 output rows per thread (2 packed pairs) + SSIM ----
    v2f m1p[2], m2p[2], e11p[2], e22p[2], e12p[2];
    #pragma unroll
    for (int jp = 0; jp < 2; ++jp) {
      m1p[jp] = 0.f; m2p[jp] = 0.f; e11p[jp] = 0.f; e22p[jp] = 0.f; e12p[jp] = 0.f;
    }

    const int y0l = RB * kc + yg * 4;          // local first output row
    int idx = y0l % RING;
    #pragma unroll
    for (int rr = 0; rr < 14; ++rr) {
      const int a = (xg3 * RING + idx) * SLOT;
      float4 v4 = *(const float4*)&sR[a + 4 * cl];
      float  v5 = sR[a + 32 + cl];
      v2f x1; x1.x = v4.x; x1.y = v4.x;
      v2f x2; x2.x = v4.y; x2.y = v4.y;
      v2f x3; x3.x = v4.z; x3.y = v4.z;
      v2f x4; x4.x = v4.w; x4.y = v4.w;
      v2f x5; x5.x = v5;   x5.y = v5;
      if (rr < 12) {                           // jp=0, m = rr
        v2f w = wp[rr];
        m1p[0]  = __builtin_elementwise_fma(w, x1, m1p[0]);
        m2p[0]  = __builtin_elementwise_fma(w, x2, m2p[0]);
        e11p[0] = __builtin_elementwise_fma(w, x3, e11p[0]);
        e22p[0] = __builtin_elementwise_fma(w, x4, e22p[0]);
        e12p[0] = __builtin_elementwise_fma(w, x5, e12p[0]);
      }
      if (rr >= 2) {                           // jp=1, m = rr-2
        v2f w = wp[rr - 2];
        m1p[1]  = __builtin_elementwise_fma(w, x1, m1p[1]);
        m2p[1]  = __builtin_elementwise_fma(w, x2, m2p[1]);
        e11p[1] = __builtin_elementwise_fma(w, x3, e11p[1]);
        e22p[1] = __builtin_elementwise_fma(w, x4, e22p[1]);
        e12p[1] = __builtin_elementwise_fma(w, x5, e12p[1]);
      }
      idx++; if (idx == RING) idx = 0;
    }

    #pragma unroll
    for (int jp = 0; jp < 2; ++jp) {
      v2f m1 = m1p[jp], m2 = m2p[jp];
      v2f m1s = m1 * m1, m2s = m2 * m2, m12 = m1 * m2;
      v2f s11 = e11p[jp] - m1s, s22 = e22p[jp] - m2s, s12 = e12p[jp] - m12;
      v2f num = (2.f * m12 + C1c) * (2.f * s12 + C2c);
      v2f den = (m1s + m2s + C1c) * (s11 + s22 + C2c);
      lsum += (1.f - num.x * __builtin_amdgcn_rcpf(den.x)) * 0.5f;
      lsum += (1.f - num.y * __builtin_amdgcn_rcpf(den.y)) * 0.5f;
    }
    __syncthreads();
  }

  // wave reduce -> block reduce -> ONE atomic per block (6144 total)
  #pragma unroll
  for (int off = 32; off > 0; off >>= 1) lsum += __shfl_down(lsum, off);
  if ((tid & 63) == 0) sR[tid >> 6] = lsum;
  __syncthreads();
  if (tid == 0) atomicAdd(ws, sR[0] + sR[1] + sR[2] + sR[3]);
}

extern "C" void kernel_launch(void* const* d_in, const int* in_sizes, int n_in,
                              void* d_out, int out_size, void* d_ws, size_t ws_size,
                              hipStream_t stream) {
  const float* im1 = (const float*)d_in[0];
  const float* im2 = (const float*)d_in[1];
  const float* gk  = (const float*)d_in[2];
  float* out = (float*)d_out;
  float* ws  = (float*)d_ws;

  hipLaunchKernelGGL(dssim_zero, dim3(1), dim3(1), 0, stream, ws);
  hipLaunchKernelGGL(dssim_main, dim3(NIMG * CTILES * SEGN), dim3(256), 0, stream,
                     im1, im2, gk, ws);
  hipLaunchKernelGGL(dssim_final, dim3(1), dim3(1), 0, stream, ws, out);
}